// Round 1
// baseline (2034.698 us; speedup 1.0000x reference)
//
#include <hip/hip_runtime.h>
#include <hip/hip_bf16.h>

// Lovasz loss via bucketed counting-sort reformulation.
// N=32, C=2, H=W=512 -> P=2^18, 64 segments of 262144 elements.
//
// Key identity: at sorted position i (descending d), with s = cumsum(mask):
//   mask=1 element: grad = 1/union, union = gts + i0 - s0 (constant within a
//                   run of mask1 at the same "prefix state")
//   mask=0 element: grad = inter/((U+j)(U+j+1))  -> telescopes over a run
// Sum of grad over any block of tied d depends only on boundary (i, s), so
// bucketing by d with width w introduces error <= ~2.5w per segment.
// B=8192 -> w=1.2e-4 -> final loss error ~ w/16 ~ 8e-6 << 1.67e-4 threshold.

#define NB    8192      // buckets (d in [0,1], uniform)
#define NBLOG 13
#define NSEG  64        // C*N
#define PLOG  18        // P = 262144
#define NN    32

// ---------------- Phase 1: histogram ----------------
// hist[seg][b] packs (count_mask1 << 32) | count_mask0 as u64 (one atomic/elem)
__global__ __launch_bounds__(256) void lovasz_hist_kernel(
    const float* __restrict__ x, const int* __restrict__ tgt,
    unsigned long long* __restrict__ hist, unsigned* __restrict__ cnt_gt)
{
    const long long total  = (long long)NN << PLOG;          // 8388608 (n,p) pairs
    const long long stride = (long long)gridDim.x * blockDim.x;
    for (long long q = (long long)blockIdx.x * blockDim.x + threadIdx.x;
         q < total; q += stride) {
        int n = (int)(q >> PLOG);
        int p = (int)(q & ((1 << PLOG) - 1));
        int tv = tgt[q];
        const float* xb = x + (((long long)n * 2) << PLOG);
#pragma unroll
        for (int c = 0; c < 2; ++c) {
            float xv = xb[((long long)c << PLOG) + p];
            int   m  = (tv == c) ? 1 : 0;
            float d  = fabsf((float)m - xv);
            int   b  = (int)(d * (float)NB);
            if (b > NB - 1) b = NB - 1;
            int seg = (c << 5) | n;
            atomicAdd(&hist[((long long)seg << NBLOG) + b],
                      m ? (1ULL << 32) : 1ULL);
            // exact count of (x > 0.25) for the empty-skip condition.
            // 64|P and stride%64==0 -> every wave lies in one segment.
            unsigned long long ball = __ballot(xv > 0.25f);
            if ((threadIdx.x & 63) == 0)
                atomicAdd(&cnt_gt[seg], (unsigned)__popcll(ball));
        }
    }
}

// ---------------- Phase 2: per-segment scan over buckets ----------------
#define CHUNK (NB / 256)   // 32 buckets per thread

__global__ __launch_bounds__(256) void lovasz_scan_kernel(
    const unsigned long long* __restrict__ hist,
    const unsigned* __restrict__ cnt_gt,
    const float* __restrict__ cw, const float* __restrict__ tw,
    float* __restrict__ loss_sum, unsigned* __restrict__ valid_cnt)
{
    const int seg = blockIdx.x;
    const int tid = threadIdx.x;
    const unsigned long long* h = hist + ((long long)seg << NBLOG);

    // Pass A: per-thread totals over its chunk (descending-order chunking).
    unsigned tot_all = 0, tot1 = 0;
    int maxb_local = -1;
    for (int j = 0; j < CHUNK; ++j) {
        int b = (NB - 1) - (tid * CHUNK + j);
        unsigned long long v = h[b];
        unsigned n0 = (unsigned)v, n1 = (unsigned)(v >> 32);
        tot_all += n0 + n1; tot1 += n1;
        if (maxb_local < 0 && (n0 | n1)) maxb_local = b;  // largest nonempty b in chunk
    }

    __shared__ unsigned sa[256], s1[256];
    __shared__ int smax[256];
    sa[tid] = tot_all; s1[tid] = tot1; smax[tid] = maxb_local;
    __syncthreads();
    // Hillis-Steele inclusive scan over the 256 thread totals.
    for (int off = 1; off < 256; off <<= 1) {
        unsigned va = 0, v1 = 0;
        if (tid >= off) { va = sa[tid - off]; v1 = s1[tid - off]; }
        __syncthreads();
        sa[tid] += va; s1[tid] += v1;
        __syncthreads();
    }
    const unsigned gts = s1[255];
    const unsigned i0  = (tid > 0) ? sa[tid - 1] : 0;   // elements in higher buckets
    const unsigned sc0 = (tid > 0) ? s1[tid - 1] : 0;   // mask1 in higher buckets
    __syncthreads();
    for (int off = 128; off > 0; off >>= 1) {           // max-reduce nonempty bucket
        if (tid < off) smax[tid] = max(smax[tid], smax[tid + off]);
        __syncthreads();
    }
    const int max_b = smax[0];

    // Pass B: walk own chunk with running (i, s), closed-form per bucket.
    double per_local = 0.0;
    if (gts > 0) {
        unsigned i = i0, s = sc0;
        for (int j = 0; j < CHUNK; ++j) {
            int b = (NB - 1) - (tid * CHUNK + j);
            unsigned long long v = h[b];
            unsigned n0 = (unsigned)v, n1 = (unsigned)(v >> 32);
            if (n0 | n1) {
                double d_rep = ((double)b + 0.5) * (1.0 / (double)NB);
                unsigned U = gts + i - s;                  // union for this bucket
                if (n1) per_local += (double)n1 * d_rep / (double)U;
                s += n1;
                unsigned inter = gts - s;
                if (n0 && inter)                           // telescoped mask0 run
                    per_local += d_rep * (double)inter * (double)n0 /
                                 ((double)U * (double)(U + n0));
                i += n0 + n1;
            }
        }
    }

    __shared__ double sd[256];
    sd[tid] = per_local; __syncthreads();
    for (int off = 128; off > 0; off >>= 1) {
        if (tid < off) sd[tid] += sd[tid + off];
        __syncthreads();
    }

    if (tid == 0) {
        double per = sd[0];
        if (gts == 0)   // all-grad mass on first element: per = max distance
            per = (max_b >= 0) ? ((double)max_b + 0.5) * (1.0 / (double)NB) : 0.0;
        const int c = seg >> 5, n = seg & 31;
        const bool empty = (gts == 0) && (cnt_gt[seg] == 0);
        const float cwv = cw[c], twv = tw[n];
        if ((cwv != 0.0f) && !empty) {
            atomicAdd(loss_sum, (float)(per * (double)twv * (double)cwv));
            atomicAdd(valid_cnt, 1u);
        }
    }
}

// ---------------- Phase 3: finalize ----------------
__global__ void lovasz_final_kernel(const float* __restrict__ loss_sum,
                                    const unsigned* __restrict__ valid_cnt,
                                    float* __restrict__ out)
{
    out[0] = loss_sum[0] / (float)NN / (float)valid_cnt[0];
}

extern "C" void kernel_launch(void* const* d_in, const int* in_sizes, int n_in,
                              void* d_out, int out_size, void* d_ws, size_t ws_size,
                              hipStream_t stream)
{
    const float* x   = (const float*)d_in[0];   // [32,2,512,512] f32
    const int*   tgt = (const int*)d_in[1];     // [32,512,512] int
    const float* cw  = (const float*)d_in[2];   // [2]
    const float* tw  = (const float*)d_in[3];   // [32]
    float* out = (float*)d_out;

    const size_t HIST_BYTES = (size_t)NSEG * NB * sizeof(unsigned long long); // 4 MiB
    unsigned long long* hist = (unsigned long long*)d_ws;
    unsigned* cnt_gt    = (unsigned*)((char*)d_ws + HIST_BYTES);
    float*    loss_sum  = (float*)((char*)d_ws + HIST_BYTES + 256);
    unsigned* valid_cnt = (unsigned*)((char*)d_ws + HIST_BYTES + 260);

    hipMemsetAsync(d_ws, 0, HIST_BYTES + 512, stream);
    lovasz_hist_kernel<<<8192, 256, 0, stream>>>(x, tgt, hist, cnt_gt);
    lovasz_scan_kernel<<<NSEG, 256, 0, stream>>>(hist, cnt_gt, cw, tw,
                                                 loss_sum, valid_cnt);
    lovasz_final_kernel<<<1, 1, 0, stream>>>(loss_sum, valid_cnt, out);
}

// Round 2
// 219.370 us; speedup vs baseline: 9.2752x; 9.2752x over previous
//
#include <hip/hip_runtime.h>
#include <hip/hip_bf16.h>

// Lovasz loss via bucketed counting-sort reformulation. See R1 notes.
// R2: global-atomic histogram (527 MB coherence writes, 1917 us) replaced by
// LDS-private histograms + plain-store partials + reduction in the scan kernel.

#define NB    8192      // buckets (d in [0,1], uniform); error ~ w/16 ~ 8e-6
#define NBLOG 13
#define NSEG  64        // C*N
#define PLOG  18        // P = 262144
#define NN    32
#define PTOT  (1 << PLOG)
#define CHUNK (NB / 256)   // 32 buckets per thread in the scan

// ---------------- Phase 1 (fast path): LDS histogram ----------------
// grid = NN*Bn blocks; block g handles sample n=g/Bn, slice sl=g%Bn of p.
// LDS hist: [2][NB] u32 packed (count_mask1 << 16) | count_mask0.
// Max per-bucket count = P/Bn <= 65536? Bn>=8 guarantees <= 32768. (Bn=4 is
// 65536 worst case == overflow only if EVERY element lands in one bucket --
// impossible for uniform-random inputs; accepted for the fallback tier.)
__global__ __launch_bounds__(256) void hist_lds_kernel(
    const float* __restrict__ x, const int* __restrict__ tgt,
    unsigned* __restrict__ partial, unsigned* __restrict__ cnt_gt, int Bn)
{
    __shared__ unsigned hl[2 * NB];   // 64 KB
    __shared__ unsigned red[512];
    const int g   = blockIdx.x;
    const int n   = g / Bn;
    const int sl  = g - n * Bn;
    const int tid = threadIdx.x;

    for (int i = tid; i < 2 * NB; i += 256) hl[i] = 0;
    __syncthreads();

    const int pairs = PTOT / Bn;
    const int base  = sl * pairs;
    const float* x0 = x + (((long long)n * 2) << PLOG);
    const float* x1 = x0 + PTOT;
    const int*   tg = tgt + ((long long)n << PLOG);

    unsigned cgt0 = 0, cgt1 = 0;
    for (int off = tid * 4; off < pairs; off += 256 * 4) {
        const int p = base + off;
        float4 a  = *(const float4*)(x0 + p);
        float4 b  = *(const float4*)(x1 + p);
        int4   t4 = *(const int4*)(tg + p);
        float xa[4] = {a.x, a.y, a.z, a.w};
        float xb[4] = {b.x, b.y, b.z, b.w};
        int   tt[4] = {t4.x, t4.y, t4.z, t4.w};
#pragma unroll
        for (int k = 0; k < 4; ++k) {
            const bool m0 = (tt[k] == 0);
            const bool m1 = (tt[k] == 1);
            float d0 = m0 ? 1.0f - xa[k] : xa[k];
            float d1 = m1 ? 1.0f - xb[k] : xb[k];
            int b0 = (int)(d0 * (float)NB); b0 = b0 > NB - 1 ? NB - 1 : b0;
            int b1 = (int)(d1 * (float)NB); b1 = b1 > NB - 1 ? NB - 1 : b1;
            atomicAdd(&hl[b0],      m0 ? 0x10000u : 1u);
            atomicAdd(&hl[NB + b1], m1 ? 0x10000u : 1u);
            cgt0 += (xa[k] > 0.25f) ? 1u : 0u;
            cgt1 += (xb[k] > 0.25f) ? 1u : 0u;
        }
    }

    // block-reduce the (x > 0.25) counts; 2 global atomics per block total.
    red[tid] = cgt0; red[256 + tid] = cgt1;
    __syncthreads();
    for (int o = 128; o > 0; o >>= 1) {
        if (tid < o) { red[tid] += red[tid + o]; red[256 + tid] += red[256 + tid + o]; }
        __syncthreads();
    }
    if (tid == 0) {
        atomicAdd(&cnt_gt[n],      red[0]);     // seg (c=0,n)
        atomicAdd(&cnt_gt[32 + n], red[256]);   // seg (c=1,n)
    }
    // all hl atomics complete as of the first reduction barrier; flush plain.
    unsigned* outp = partial + (size_t)g * (2 * NB);
    for (int i = tid; i < 2 * NB; i += 256) outp[i] = hl[i];
}

// ---------------- Phase 2 (fast path): merge partials + scan ----------------
__global__ __launch_bounds__(256) void scan_merge_kernel(
    const unsigned* __restrict__ partial, const unsigned* __restrict__ cnt_gt,
    const float* __restrict__ cw, const float* __restrict__ tw,
    float* __restrict__ loss_sum, unsigned* __restrict__ valid_cnt, int Bn)
{
    const int seg = blockIdx.x;           // seg = (c<<5)|n
    const int c = seg >> 5, n = seg & 31;
    const int tid = threadIdx.x;

    __shared__ unsigned mh0[NB], mh1[NB];    // 64 KB merged counts
    __shared__ unsigned sa[256], s1[256];
    __shared__ int smax[256];
    __shared__ double sd[256];

    // coalesced merge; MUST unpack before accumulating (16-bit fields carry).
    for (int i = tid; i < NB; i += 256) {
        unsigned v0 = 0, v1 = 0;
        for (int s = 0; s < Bn; ++s) {
            unsigned v = partial[(((size_t)(n * Bn + s) * 2) + c) * NB + i];
            v0 += v & 0xFFFFu; v1 += v >> 16;
        }
        mh0[i] = v0; mh1[i] = v1;
    }
    __syncthreads();

    // Pass A: per-thread totals over its descending chunk.
    unsigned tot_all = 0, tot1 = 0;
    int maxb_local = -1;
    for (int j = 0; j < CHUNK; ++j) {
        int b = (NB - 1) - (tid * CHUNK + j);
        unsigned n0 = mh0[b], n1 = mh1[b];
        tot_all += n0 + n1; tot1 += n1;
        if (maxb_local < 0 && (n0 | n1)) maxb_local = b;
    }
    sa[tid] = tot_all; s1[tid] = tot1; smax[tid] = maxb_local;
    __syncthreads();
    for (int off = 1; off < 256; off <<= 1) {   // Hillis-Steele inclusive scan
        unsigned va = 0, v1 = 0;
        if (tid >= off) { va = sa[tid - off]; v1 = s1[tid - off]; }
        __syncthreads();
        sa[tid] += va; s1[tid] += v1;
        __syncthreads();
    }
    const unsigned gts = s1[255];
    const unsigned i0  = (tid > 0) ? sa[tid - 1] : 0;
    const unsigned sc0 = (tid > 0) ? s1[tid - 1] : 0;
    __syncthreads();
    for (int off = 128; off > 0; off >>= 1) {
        if (tid < off) smax[tid] = max(smax[tid], smax[tid + off]);
        __syncthreads();
    }
    const int max_b = smax[0];

    // Pass B: closed-form contribution per bucket with running (i, s).
    double per_local = 0.0;
    if (gts > 0) {
        unsigned i = i0, s = sc0;
        for (int j = 0; j < CHUNK; ++j) {
            int b = (NB - 1) - (tid * CHUNK + j);
            unsigned n0 = mh0[b], n1 = mh1[b];
            if (n0 | n1) {
                double d_rep = ((double)b + 0.5) * (1.0 / (double)NB);
                unsigned U = gts + i - s;
                if (n1) per_local += (double)n1 * d_rep / (double)U;
                s += n1;
                unsigned inter = gts - s;
                if (n0 && inter)
                    per_local += d_rep * (double)inter * (double)n0 /
                                 ((double)U * (double)(U + n0));
                i += n0 + n1;
            }
        }
    }
    sd[tid] = per_local; __syncthreads();
    for (int off = 128; off > 0; off >>= 1) {
        if (tid < off) sd[tid] += sd[tid + off];
        __syncthreads();
    }
    if (tid == 0) {
        double per = sd[0];
        if (gts == 0)
            per = (max_b >= 0) ? ((double)max_b + 0.5) * (1.0 / (double)NB) : 0.0;
        const bool empty = (gts == 0) && (cnt_gt[seg] == 0);
        const float cwv = cw[c], twv = tw[n];
        if ((cwv != 0.0f) && !empty) {
            atomicAdd(loss_sum, (float)(per * (double)twv * (double)cwv));
            atomicAdd(valid_cnt, 1u);
        }
    }
}

// ---------------- Fallback path (tiny ws): R1 global-atomic kernels ---------
__global__ __launch_bounds__(256) void lovasz_hist_kernel(
    const float* __restrict__ x, const int* __restrict__ tgt,
    unsigned long long* __restrict__ hist, unsigned* __restrict__ cnt_gt)
{
    const long long total  = (long long)NN << PLOG;
    const long long stride = (long long)gridDim.x * blockDim.x;
    for (long long q = (long long)blockIdx.x * blockDim.x + threadIdx.x;
         q < total; q += stride) {
        int n = (int)(q >> PLOG);
        int p = (int)(q & ((1 << PLOG) - 1));
        int tv = tgt[q];
        const float* xb = x + (((long long)n * 2) << PLOG);
#pragma unroll
        for (int c = 0; c < 2; ++c) {
            float xv = xb[((long long)c << PLOG) + p];
            int   m  = (tv == c) ? 1 : 0;
            float d  = fabsf((float)m - xv);
            int   b  = (int)(d * (float)NB);
            if (b > NB - 1) b = NB - 1;
            int seg = (c << 5) | n;
            atomicAdd(&hist[((long long)seg << NBLOG) + b],
                      m ? (1ULL << 32) : 1ULL);
            unsigned long long ball = __ballot(xv > 0.25f);
            if ((threadIdx.x & 63) == 0)
                atomicAdd(&cnt_gt[seg], (unsigned)__popcll(ball));
        }
    }
}

__global__ __launch_bounds__(256) void lovasz_scan_kernel(
    const unsigned long long* __restrict__ hist,
    const unsigned* __restrict__ cnt_gt,
    const float* __restrict__ cw, const float* __restrict__ tw,
    float* __restrict__ loss_sum, unsigned* __restrict__ valid_cnt)
{
    const int seg = blockIdx.x;
    const int tid = threadIdx.x;
    const unsigned long long* h = hist + ((long long)seg << NBLOG);
    unsigned tot_all = 0, tot1 = 0;
    int maxb_local = -1;
    for (int j = 0; j < CHUNK; ++j) {
        int b = (NB - 1) - (tid * CHUNK + j);
        unsigned long long v = h[b];
        unsigned n0 = (unsigned)v, n1 = (unsigned)(v >> 32);
        tot_all += n0 + n1; tot1 += n1;
        if (maxb_local < 0 && (n0 | n1)) maxb_local = b;
    }
    __shared__ unsigned sa[256], s1[256];
    __shared__ int smax[256];
    sa[tid] = tot_all; s1[tid] = tot1; smax[tid] = maxb_local;
    __syncthreads();
    for (int off = 1; off < 256; off <<= 1) {
        unsigned va = 0, v1 = 0;
        if (tid >= off) { va = sa[tid - off]; v1 = s1[tid - off]; }
        __syncthreads();
        sa[tid] += va; s1[tid] += v1;
        __syncthreads();
    }
    const unsigned gts = s1[255];
    const unsigned i0  = (tid > 0) ? sa[tid - 1] : 0;
    const unsigned sc0 = (tid > 0) ? s1[tid - 1] : 0;
    __syncthreads();
    for (int off = 128; off > 0; off >>= 1) {
        if (tid < off) smax[tid] = max(smax[tid], smax[tid + off]);
        __syncthreads();
    }
    const int max_b = smax[0];
    double per_local = 0.0;
    if (gts > 0) {
        unsigned i = i0, s = sc0;
        for (int j = 0; j < CHUNK; ++j) {
            int b = (NB - 1) - (tid * CHUNK + j);
            unsigned long long v = h[b];
            unsigned n0 = (unsigned)v, n1 = (unsigned)(v >> 32);
            if (n0 | n1) {
                double d_rep = ((double)b + 0.5) * (1.0 / (double)NB);
                unsigned U = gts + i - s;
                if (n1) per_local += (double)n1 * d_rep / (double)U;
                s += n1;
                unsigned inter = gts - s;
                if (n0 && inter)
                    per_local += d_rep * (double)inter * (double)n0 /
                                 ((double)U * (double)(U + n0));
                i += n0 + n1;
            }
        }
    }
    __shared__ double sd[256];
    sd[tid] = per_local; __syncthreads();
    for (int off = 128; off > 0; off >>= 1) {
        if (tid < off) sd[tid] += sd[tid + off];
        __syncthreads();
    }
    if (tid == 0) {
        double per = sd[0];
        if (gts == 0)
            per = (max_b >= 0) ? ((double)max_b + 0.5) * (1.0 / (double)NB) : 0.0;
        const int c = seg >> 5, n = seg & 31;
        const bool empty = (gts == 0) && (cnt_gt[seg] == 0);
        const float cwv = cw[c], twv = tw[n];
        if ((cwv != 0.0f) && !empty) {
            atomicAdd(loss_sum, (float)(per * (double)twv * (double)cwv));
            atomicAdd(valid_cnt, 1u);
        }
    }
}

// ---------------- Phase 3: finalize ----------------
__global__ void lovasz_final_kernel(const float* __restrict__ loss_sum,
                                    const unsigned* __restrict__ valid_cnt,
                                    float* __restrict__ out)
{
    out[0] = loss_sum[0] / (float)NN / (float)valid_cnt[0];
}

extern "C" void kernel_launch(void* const* d_in, const int* in_sizes, int n_in,
                              void* d_out, int out_size, void* d_ws, size_t ws_size,
                              hipStream_t stream)
{
    const float* x   = (const float*)d_in[0];   // [32,2,512,512] f32
    const int*   tgt = (const int*)d_in[1];     // [32,512,512] int
    const float* cw  = (const float*)d_in[2];   // [2]
    const float* tw  = (const float*)d_in[3];   // [32]
    float* out = (float*)d_out;

    // fast-path ws layout: [0,256) cnt_gt, [256,260) loss, [260,264) valid,
    // [512, ...) partial histograms (NN*Bn * 2*NB u32).
    const size_t per_bn = (size_t)NN * 2 * NB * sizeof(unsigned);  // 2 MiB per Bn
    int Bn = 0;
    if      (ws_size >= 512 + 16 * per_bn) Bn = 16;
    else if (ws_size >= 512 +  8 * per_bn) Bn = 8;
    else if (ws_size >= 512 +  4 * per_bn) Bn = 4;

    if (Bn > 0) {
        unsigned* cnt_gt    = (unsigned*)d_ws;
        float*    loss_sum  = (float*)((char*)d_ws + 256);
        unsigned* valid_cnt = (unsigned*)((char*)d_ws + 260);
        unsigned* partial   = (unsigned*)((char*)d_ws + 512);
        hipMemsetAsync(d_ws, 0, 512, stream);
        hist_lds_kernel<<<NN * Bn, 256, 0, stream>>>(x, tgt, partial, cnt_gt, Bn);
        scan_merge_kernel<<<NSEG, 256, 0, stream>>>(partial, cnt_gt, cw, tw,
                                                    loss_sum, valid_cnt, Bn);
        lovasz_final_kernel<<<1, 1, 0, stream>>>(loss_sum, valid_cnt, out);
    } else {
        // R1 fallback: global-atomic histogram (slow but needs only ~4.2 MiB).
        const size_t HIST_BYTES = (size_t)NSEG * NB * sizeof(unsigned long long);
        unsigned long long* hist = (unsigned long long*)d_ws;
        unsigned* cnt_gt    = (unsigned*)((char*)d_ws + HIST_BYTES);
        float*    loss_sum  = (float*)((char*)d_ws + HIST_BYTES + 256);
        unsigned* valid_cnt = (unsigned*)((char*)d_ws + HIST_BYTES + 260);
        hipMemsetAsync(d_ws, 0, HIST_BYTES + 512, stream);
        lovasz_hist_kernel<<<8192, 256, 0, stream>>>(x, tgt, hist, cnt_gt);
        lovasz_scan_kernel<<<NSEG, 256, 0, stream>>>(hist, cnt_gt, cw, tw,
                                                     loss_sum, valid_cnt);
        lovasz_final_kernel<<<1, 1, 0, stream>>>(loss_sum, valid_cnt, out);
    }
}

// Round 3
// 154.206 us; speedup vs baseline: 13.1947x; 1.4226x over previous
//
#include <hip/hip_runtime.h>
#include <hip/hip_bf16.h>

// Lovasz loss via bucketed counting-sort reformulation.
// R2: LDS-private histograms replaced global atomics (1917 -> 84+hist us).
// R3: scan_merge was latency-bound (64 blocks, 2.6% occupancy, 512 KB serial
//     reads each). Split merge into a 1024-block kernel (in-place into slices
//     0/1 of the partial buffer), NB 8192->4096 + Bn 16->32 (hist 4 blocks/CU,
//     same 32 MiB partial footprint), scan in float (no f64 divides).

#define NB    4096      // buckets (d in [0,1]); final err ~2e-6 << 1.67e-4
#define NSEG  64        // C*N
#define PLOG  18        // P = 262144
#define NN    32
#define PTOT  (1 << PLOG)
#define CHUNK (NB / 256)   // 16 buckets per thread in the scan

// partial layout: [n][slice][c][b] u32 packed (n1<<16)|n0.
// After merge_kernel: slice0 holds merged n0, slice1 holds merged n1 (u32).

// ---------------- Phase 1: LDS histogram ----------------
__global__ __launch_bounds__(256) void hist_lds_kernel(
    const float* __restrict__ x, const int* __restrict__ tgt,
    unsigned* __restrict__ partial, unsigned* __restrict__ cnt_gt, int Bn)
{
    __shared__ unsigned hl[2 * NB];   // 32 KB
    __shared__ unsigned red[512];     // 2 KB
    const int g   = blockIdx.x;
    const int n   = g / Bn;
    const int sl  = g - n * Bn;
    const int tid = threadIdx.x;

    for (int i = tid; i < 2 * NB; i += 256) hl[i] = 0;
    __syncthreads();

    const int pairs = PTOT / Bn;      // 8192 at Bn=32 -> u16 fields safe
    const int base  = sl * pairs;
    const float* x0 = x + (((long long)n * 2) << PLOG);
    const float* x1 = x0 + PTOT;
    const int*   tg = tgt + ((long long)n << PLOG);

    unsigned cgt0 = 0, cgt1 = 0;
    for (int off = tid * 4; off < pairs; off += 256 * 4) {
        const int p = base + off;
        float4 a  = *(const float4*)(x0 + p);
        float4 b  = *(const float4*)(x1 + p);
        int4   t4 = *(const int4*)(tg + p);
        float xa[4] = {a.x, a.y, a.z, a.w};
        float xb[4] = {b.x, b.y, b.z, b.w};
        int   tt[4] = {t4.x, t4.y, t4.z, t4.w};
#pragma unroll
        for (int k = 0; k < 4; ++k) {
            const bool m0 = (tt[k] == 0);
            const bool m1 = (tt[k] == 1);
            float d0 = m0 ? 1.0f - xa[k] : xa[k];
            float d1 = m1 ? 1.0f - xb[k] : xb[k];
            int b0 = (int)(d0 * (float)NB); b0 = b0 > NB - 1 ? NB - 1 : b0;
            int b1 = (int)(d1 * (float)NB); b1 = b1 > NB - 1 ? NB - 1 : b1;
            atomicAdd(&hl[b0],      m0 ? 0x10000u : 1u);
            atomicAdd(&hl[NB + b1], m1 ? 0x10000u : 1u);
            cgt0 += (xa[k] > 0.25f) ? 1u : 0u;
            cgt1 += (xb[k] > 0.25f) ? 1u : 0u;
        }
    }

    // block-reduce the (x > 0.25) counts; 2 global atomics per block total.
    red[tid] = cgt0; red[256 + tid] = cgt1;
    __syncthreads();
    for (int o = 128; o > 0; o >>= 1) {
        if (tid < o) { red[tid] += red[tid + o]; red[256 + tid] += red[256 + tid + o]; }
        __syncthreads();
    }
    if (tid == 0) {
        atomicAdd(&cnt_gt[n],      red[0]);     // seg (c=0,n)
        atomicAdd(&cnt_gt[32 + n], red[256]);   // seg (c=1,n)
    }
    // all hl atomics complete as of the reduction barriers; flush plain stores.
    unsigned* outp = partial + (size_t)g * (2 * NB);
    for (int i = tid; i < 2 * NB; i += 256) outp[i] = hl[i];
}

// ---------------- Phase 2a: parallel merge (in place) ----------------
// grid = NSEG * (NB/256). Block: seg = bid/(NB/256), bucket chunk of 256.
// Reads Bn packed slices, writes merged n0 -> slice0 slot, n1 -> slice1 slot.
// Each thread owns one (seg,b): reads and writes only its own addresses.
__global__ __launch_bounds__(256) void merge_kernel(
    unsigned* __restrict__ partial, int Bn)
{
    const int parts = NB / 256;
    const int seg  = blockIdx.x / parts;
    const int part = blockIdx.x - seg * parts;
    const int c = seg >> 5, n = seg & 31;
    const int b = part * 256 + threadIdx.x;

    unsigned v0 = 0, v1 = 0;
    for (int s = 0; s < Bn; ++s) {
        unsigned v = partial[(((size_t)(n * Bn + s) * 2) + c) * NB + b];
        v0 += v & 0xFFFFu; v1 += v >> 16;
    }
    partial[(((size_t)(n * Bn + 0) * 2) + c) * NB + b] = v0;
    partial[(((size_t)(n * Bn + 1) * 2) + c) * NB + b] = v1;
}

// ---------------- Phase 2b: per-segment scan ----------------
__global__ __launch_bounds__(256) void scan_kernel(
    const unsigned* __restrict__ partial, const unsigned* __restrict__ cnt_gt,
    const float* __restrict__ cw, const float* __restrict__ tw,
    float* __restrict__ loss_sum, unsigned* __restrict__ valid_cnt, int Bn)
{
    const int seg = blockIdx.x;           // seg = (c<<5)|n
    const int c = seg >> 5, n = seg & 31;
    const int tid = threadIdx.x;

    __shared__ unsigned mh0[NB], mh1[NB];    // 32 KB merged counts
    __shared__ unsigned sa[256], s1[256];
    __shared__ int smax[256];
    __shared__ float sd[256];

    const unsigned* p0 = partial + (((size_t)(n * Bn + 0) * 2) + c) * NB;
    const unsigned* p1 = partial + (((size_t)(n * Bn + 1) * 2) + c) * NB;
    for (int i = tid; i < NB; i += 256) { mh0[i] = p0[i]; mh1[i] = p1[i]; }
    __syncthreads();

    // Pass A: per-thread totals over its descending chunk.
    unsigned tot_all = 0, tot1 = 0;
    int maxb_local = -1;
    for (int j = 0; j < CHUNK; ++j) {
        int b = (NB - 1) - (tid * CHUNK + j);
        unsigned n0 = mh0[b], n1 = mh1[b];
        tot_all += n0 + n1; tot1 += n1;
        if (maxb_local < 0 && (n0 | n1)) maxb_local = b;
    }
    sa[tid] = tot_all; s1[tid] = tot1; smax[tid] = maxb_local;
    __syncthreads();
    for (int off = 1; off < 256; off <<= 1) {   // Hillis-Steele inclusive scan
        unsigned va = 0, v1 = 0;
        if (tid >= off) { va = sa[tid - off]; v1 = s1[tid - off]; }
        __syncthreads();
        sa[tid] += va; s1[tid] += v1;
        __syncthreads();
    }
    const unsigned gts = s1[255];
    const unsigned i0  = (tid > 0) ? sa[tid - 1] : 0;
    const unsigned sc0 = (tid > 0) ? s1[tid - 1] : 0;
    __syncthreads();
    for (int off = 128; off > 0; off >>= 1) {
        if (tid < off) smax[tid] = max(smax[tid], smax[tid + off]);
        __syncthreads();
    }
    const int max_b = smax[0];

    // Pass B: closed-form contribution per bucket with running (i, s).
    // All in float: counts <= 2^18 are float-exact; rel err ~1e-7/term.
    float per_local = 0.0f;
    if (gts > 0) {
        unsigned i = i0, s = sc0;
        for (int j = 0; j < CHUNK; ++j) {
            int b = (NB - 1) - (tid * CHUNK + j);
            unsigned n0 = mh0[b], n1 = mh1[b];
            if (n0 | n1) {
                float d_rep = ((float)b + 0.5f) * (1.0f / (float)NB);
                float U = (float)(gts + i - s);
                if (n1) per_local += (float)n1 * d_rep / U;
                s += n1;
                unsigned inter = gts - s;
                if (n0 && inter)
                    per_local += d_rep * (float)inter * (float)n0 /
                                 (U * (U + (float)n0));
                i += n0 + n1;
            }
        }
    }
    sd[tid] = per_local; __syncthreads();
    for (int off = 128; off > 0; off >>= 1) {
        if (tid < off) sd[tid] += sd[tid + off];
        __syncthreads();
    }
    if (tid == 0) {
        float per = sd[0];
        if (gts == 0)
            per = (max_b >= 0) ? ((float)max_b + 0.5f) * (1.0f / (float)NB) : 0.0f;
        const bool empty = (gts == 0) && (cnt_gt[seg] == 0);
        const float cwv = cw[c], twv = tw[n];
        if ((cwv != 0.0f) && !empty) {
            atomicAdd(loss_sum, per * twv * cwv);
            atomicAdd(valid_cnt, 1u);
        }
    }
}

// ---------------- Fallback path (tiny ws): R1 global-atomic kernels ---------
__global__ __launch_bounds__(256) void lovasz_hist_kernel(
    const float* __restrict__ x, const int* __restrict__ tgt,
    unsigned long long* __restrict__ hist, unsigned* __restrict__ cnt_gt)
{
    const long long total  = (long long)NN << PLOG;
    const long long stride = (long long)gridDim.x * blockDim.x;
    for (long long q = (long long)blockIdx.x * blockDim.x + threadIdx.x;
         q < total; q += stride) {
        int n = (int)(q >> PLOG);
        int p = (int)(q & ((1 << PLOG) - 1));
        int tv = tgt[q];
        const float* xb = x + (((long long)n * 2) << PLOG);
#pragma unroll
        for (int c = 0; c < 2; ++c) {
            float xv = xb[((long long)c << PLOG) + p];
            int   m  = (tv == c) ? 1 : 0;
            float d  = fabsf((float)m - xv);
            int   b  = (int)(d * (float)NB);
            if (b > NB - 1) b = NB - 1;
            int seg = (c << 5) | n;
            atomicAdd(&hist[((long long)seg * NB) + b],
                      m ? (1ULL << 32) : 1ULL);
            unsigned long long ball = __ballot(xv > 0.25f);
            if ((threadIdx.x & 63) == 0)
                atomicAdd(&cnt_gt[seg], (unsigned)__popcll(ball));
        }
    }
}

__global__ __launch_bounds__(256) void lovasz_scan_kernel(
    const unsigned long long* __restrict__ hist,
    const unsigned* __restrict__ cnt_gt,
    const float* __restrict__ cw, const float* __restrict__ tw,
    float* __restrict__ loss_sum, unsigned* __restrict__ valid_cnt)
{
    const int seg = blockIdx.x;
    const int tid = threadIdx.x;
    const unsigned long long* h = hist + ((long long)seg * NB);
    unsigned tot_all = 0, tot1 = 0;
    int maxb_local = -1;
    for (int j = 0; j < CHUNK; ++j) {
        int b = (NB - 1) - (tid * CHUNK + j);
        unsigned long long v = h[b];
        unsigned n0 = (unsigned)v, n1 = (unsigned)(v >> 32);
        tot_all += n0 + n1; tot1 += n1;
        if (maxb_local < 0 && (n0 | n1)) maxb_local = b;
    }
    __shared__ unsigned sa[256], s1[256];
    __shared__ int smax[256];
    sa[tid] = tot_all; s1[tid] = tot1; smax[tid] = maxb_local;
    __syncthreads();
    for (int off = 1; off < 256; off <<= 1) {
        unsigned va = 0, v1 = 0;
        if (tid >= off) { va = sa[tid - off]; v1 = s1[tid - off]; }
        __syncthreads();
        sa[tid] += va; s1[tid] += v1;
        __syncthreads();
    }
    const unsigned gts = s1[255];
    const unsigned i0  = (tid > 0) ? sa[tid - 1] : 0;
    const unsigned sc0 = (tid > 0) ? s1[tid - 1] : 0;
    __syncthreads();
    for (int off = 128; off > 0; off >>= 1) {
        if (tid < off) smax[tid] = max(smax[tid], smax[tid + off]);
        __syncthreads();
    }
    const int max_b = smax[0];
    double per_local = 0.0;
    if (gts > 0) {
        unsigned i = i0, s = sc0;
        for (int j = 0; j < CHUNK; ++j) {
            int b = (NB - 1) - (tid * CHUNK + j);
            unsigned long long v = h[b];
            unsigned n0 = (unsigned)v, n1 = (unsigned)(v >> 32);
            if (n0 | n1) {
                double d_rep = ((double)b + 0.5) * (1.0 / (double)NB);
                unsigned U = gts + i - s;
                if (n1) per_local += (double)n1 * d_rep / (double)U;
                s += n1;
                unsigned inter = gts - s;
                if (n0 && inter)
                    per_local += d_rep * (double)inter * (double)n0 /
                                 ((double)U * (double)(U + n0));
                i += n0 + n1;
            }
        }
    }
    __shared__ double sd[256];
    sd[tid] = per_local; __syncthreads();
    for (int off = 128; off > 0; off >>= 1) {
        if (tid < off) sd[tid] += sd[tid + off];
        __syncthreads();
    }
    if (tid == 0) {
        double per = sd[0];
        if (gts == 0)
            per = (max_b >= 0) ? ((double)max_b + 0.5) * (1.0 / (double)NB) : 0.0;
        const int c = seg >> 5, n = seg & 31;
        const bool empty = (gts == 0) && (cnt_gt[seg] == 0);
        const float cwv = cw[c], twv = tw[n];
        if ((cwv != 0.0f) && !empty) {
            atomicAdd(loss_sum, (float)(per * (double)twv * (double)cwv));
            atomicAdd(valid_cnt, 1u);
        }
    }
}

// ---------------- Phase 3: finalize ----------------
__global__ void lovasz_final_kernel(const float* __restrict__ loss_sum,
                                    const unsigned* __restrict__ valid_cnt,
                                    float* __restrict__ out)
{
    out[0] = loss_sum[0] / (float)NN / (float)valid_cnt[0];
}

extern "C" void kernel_launch(void* const* d_in, const int* in_sizes, int n_in,
                              void* d_out, int out_size, void* d_ws, size_t ws_size,
                              hipStream_t stream)
{
    const float* x   = (const float*)d_in[0];   // [32,2,512,512] f32
    const int*   tgt = (const int*)d_in[1];     // [32,512,512] int
    const float* cw  = (const float*)d_in[2];   // [2]
    const float* tw  = (const float*)d_in[3];   // [32]
    float* out = (float*)d_out;

    // ws layout: [0,256) cnt_gt, [256,260) loss, [260,264) valid,
    // [512, ...) partial histograms (NN*Bn * 2*NB u32).
    const size_t per_bn = (size_t)NN * 2 * NB * sizeof(unsigned);  // 1 MiB per Bn
    int Bn = 0;
    if      (ws_size >= 512 + 32 * per_bn) Bn = 32;  // 32 MiB (proven fits, R2)
    else if (ws_size >= 512 + 16 * per_bn) Bn = 16;
    else if (ws_size >= 512 +  8 * per_bn) Bn = 8;

    if (Bn >= 8) {
        unsigned* cnt_gt    = (unsigned*)d_ws;
        float*    loss_sum  = (float*)((char*)d_ws + 256);
        unsigned* valid_cnt = (unsigned*)((char*)d_ws + 260);
        unsigned* partial   = (unsigned*)((char*)d_ws + 512);
        hipMemsetAsync(d_ws, 0, 512, stream);
        hist_lds_kernel<<<NN * Bn, 256, 0, stream>>>(x, tgt, partial, cnt_gt, Bn);
        merge_kernel<<<NSEG * (NB / 256), 256, 0, stream>>>(partial, Bn);
        scan_kernel<<<NSEG, 256, 0, stream>>>(partial, cnt_gt, cw, tw,
                                              loss_sum, valid_cnt, Bn);
        lovasz_final_kernel<<<1, 1, 0, stream>>>(loss_sum, valid_cnt, out);
    } else {
        // R1 fallback: global-atomic histogram (slow but needs only ~2.1 MiB).
        const size_t HIST_BYTES = (size_t)NSEG * NB * sizeof(unsigned long long);
        unsigned long long* hist = (unsigned long long*)d_ws;
        unsigned* cnt_gt    = (unsigned*)((char*)d_ws + HIST_BYTES);
        float*    loss_sum  = (float*)((char*)d_ws + HIST_BYTES + 256);
        unsigned* valid_cnt = (unsigned*)((char*)d_ws + HIST_BYTES + 260);
        hipMemsetAsync(d_ws, 0, HIST_BYTES + 512, stream);
        lovasz_hist_kernel<<<8192, 256, 0, stream>>>(x, tgt, hist, cnt_gt);
        lovasz_scan_kernel<<<NSEG, 256, 0, stream>>>(hist, cnt_gt, cw, tw,
                                                     loss_sum, valid_cnt);
        lovasz_final_kernel<<<1, 1, 0, stream>>>(loss_sum, valid_cnt, out);
    }
}

// Round 4
// 149.960 us; speedup vs baseline: 13.5682x; 1.0283x over previous
//
#include <hip/hip_runtime.h>
#include <hip/hip_bf16.h>
#include <hip/hip_cooperative_groups.h>

// Lovasz loss via bucketed counting-sort reformulation.
// R2: LDS-private histograms replaced global atomics (1917 -> 219 us).
// R3: parallel merge kernel, float scan (219 -> 154; hist 42 us, ~110 us in
//     small dispatches + launch gaps).
// R4: single cooperative dispatch (hist -> merge -> scan -> final with 3
//     grid.sync), NB 2048 / Bn 64 -> 8 blocks/CU, empty-condition count
//     derived from the histogram (drops cnt_gt atomics AND the memset).

#define NB    2048      // buckets; worst-case final err 3.8e-5 << 1.67e-4
#define NSEG  64        // C*N
#define PLOG  18        // P = 262144
#define NN    32
#define PTOT  (1 << PLOG)
#define CHUNK (NB / 256)    // 8 buckets per thread in the scan
#define B0_LO (NB / 4)      // mask0: x>0.25  <=> bucket >= NB/4
#define B1_HI (3 * NB / 4)  // mask1: x>0.25  <=> bucket <  3*NB/4

namespace cg = cooperative_groups;

// partial layout: [n][slice][c][b] u32 packed (n1<<16)|n0, slice in [0,Bn).
// After merge: slice0 holds merged n0, slice1 holds merged n1 (plain u32).

// ---------------- phase bodies ----------------
__device__ __forceinline__ void hist_body(
    const float* __restrict__ x, const int* __restrict__ tgt,
    unsigned* __restrict__ partial, int Bn, int g, unsigned* hl)
{
    const int n = g / Bn, sl = g - n * Bn;
    const int tid = threadIdx.x;
    for (int i = tid; i < 2 * NB; i += 256) hl[i] = 0;
    __syncthreads();

    const int pairs = PTOT / Bn;          // 4096 at Bn=64 -> u16 fields safe
    const int base  = sl * pairs;
    const float* x0 = x + (((long long)n * 2) << PLOG);
    const float* x1 = x0 + PTOT;
    const int*   tg = tgt + ((long long)n << PLOG);

    for (int off = tid * 4; off < pairs; off += 256 * 4) {
        const int p = base + off;
        float4 a  = *(const float4*)(x0 + p);
        float4 b  = *(const float4*)(x1 + p);
        int4   t4 = *(const int4*)(tg + p);
        float xa[4] = {a.x, a.y, a.z, a.w};
        float xb[4] = {b.x, b.y, b.z, b.w};
        int   tt[4] = {t4.x, t4.y, t4.z, t4.w};
#pragma unroll
        for (int k = 0; k < 4; ++k) {
            const bool m0 = (tt[k] == 0);
            const bool m1 = (tt[k] == 1);
            float d0 = m0 ? 1.0f - xa[k] : xa[k];
            float d1 = m1 ? 1.0f - xb[k] : xb[k];
            int b0 = min((int)(d0 * (float)NB), NB - 1);
            int b1 = min((int)(d1 * (float)NB), NB - 1);
            atomicAdd(&hl[b0],      m0 ? 0x10000u : 1u);
            atomicAdd(&hl[NB + b1], m1 ? 0x10000u : 1u);
        }
    }
    __syncthreads();   // all LDS atomics visible before flush
    unsigned* outp = partial + (size_t)g * (2 * NB);
    for (int i = tid; i < 2 * NB; i += 256) outp[i] = hl[i];
}

// merge block mb handles (seg = mb/(NB/256), bucket chunk of 256).
// In-place: merged n0 -> slice0 slot, n1 -> slice1 slot (thread-owned addrs).
__device__ __forceinline__ void merge_body(unsigned* __restrict__ partial,
                                           int Bn, int mb)
{
    const int parts = NB / 256;
    const int seg  = mb / parts;
    const int part = mb - seg * parts;
    const int c = seg >> 5, n = seg & 31;
    const int b = part * 256 + threadIdx.x;

    unsigned v0 = 0, v1 = 0;
    for (int s = 0; s < Bn; ++s) {
        unsigned v = partial[(((size_t)(n * Bn + s) * 2) + c) * NB + b];
        v0 += v & 0xFFFFu; v1 += v >> 16;
    }
    partial[(((size_t)(n * Bn + 0) * 2) + c) * NB + b] = v0;
    partial[(((size_t)(n * Bn + 1) * 2) + c) * NB + b] = v1;
}

// scan block handles one segment. mh = 2*NB u32 LDS, red = 768 u32 LDS.
__device__ __forceinline__ void scan_body(
    const unsigned* __restrict__ partial,
    const float* __restrict__ cw, const float* __restrict__ tw,
    float* __restrict__ segval, unsigned* __restrict__ segvalid,
    int Bn, int seg, unsigned* mh, unsigned* red)
{
    const int c = seg >> 5, n = seg & 31;
    const int tid = threadIdx.x;

    const unsigned* p0 = partial + (((size_t)(n * Bn + 0) * 2) + c) * NB;
    const unsigned* p1 = partial + (((size_t)(n * Bn + 1) * 2) + c) * NB;
    for (int i = tid; i < NB; i += 256) { mh[i] = p0[i]; mh[NB + i] = p1[i]; }
    __syncthreads();

    // Pass A: per-thread totals over descending chunk (+ x>0.25 count).
    unsigned tot_all = 0, tot1 = 0, cgt = 0;
    int maxb_local = -1;
    for (int j = 0; j < CHUNK; ++j) {
        int b = (NB - 1) - (tid * CHUNK + j);
        unsigned n0 = mh[b], n1 = mh[NB + b];
        tot_all += n0 + n1; tot1 += n1;
        if (b >= B0_LO) cgt += n0;   // mask0: d=x, x>0.25
        if (b <  B1_HI) cgt += n1;   // mask1: d=1-x, x>0.25 <=> d<0.75
        if (maxb_local < 0 && (n0 | n1)) maxb_local = b;
    }
    unsigned* sa = red;        // [0,256)
    unsigned* s1 = red + 256;  // [256,512)
    unsigned* sc = red + 512;  // [512,768)
    sa[tid] = tot_all; s1[tid] = tot1; sc[tid] = cgt;
    __syncthreads();
    for (int off = 1; off < 256; off <<= 1) {  // Hillis-Steele inclusive scan
        unsigned va = 0, v1 = 0, vc = 0;
        if (tid >= off) { va = sa[tid - off]; v1 = s1[tid - off]; vc = sc[tid - off]; }
        __syncthreads();
        sa[tid] += va; s1[tid] += v1; sc[tid] += vc;
        __syncthreads();
    }
    const unsigned gts   = s1[255];
    const unsigned cntgt = sc[255];
    const unsigned i0  = (tid > 0) ? sa[tid - 1] : 0;
    const unsigned sc0 = (tid > 0) ? s1[tid - 1] : 0;
    __syncthreads();
    // max nonempty bucket: tree-reduce reusing sc.
    ((int*)sc)[tid] = maxb_local;
    __syncthreads();
    for (int off = 128; off > 0; off >>= 1) {
        if (tid < off) ((int*)sc)[tid] = max(((int*)sc)[tid], ((int*)sc)[tid + off]);
        __syncthreads();
    }
    const int max_b = ((int*)sc)[0];

    // Pass B: closed-form per-bucket contribution with running (i, s).
    float per_local = 0.0f;
    if (gts > 0) {
        unsigned i = i0, s = sc0;
        for (int j = 0; j < CHUNK; ++j) {
            int b = (NB - 1) - (tid * CHUNK + j);
            unsigned n0 = mh[b], n1 = mh[NB + b];
            if (n0 | n1) {
                float d_rep = ((float)b + 0.5f) * (1.0f / (float)NB);
                float U = (float)(gts + i - s);
                if (n1) per_local += (float)n1 * d_rep / U;
                s += n1;
                unsigned inter = gts - s;
                if (n0 && inter)
                    per_local += d_rep * (float)inter * (float)n0 /
                                 (U * (U + (float)n0));
                i += n0 + n1;
            }
        }
    }
    __syncthreads();
    float* sd = (float*)sa;    // reuse
    sd[tid] = per_local;
    __syncthreads();
    for (int off = 128; off > 0; off >>= 1) {
        if (tid < off) sd[tid] += sd[tid + off];
        __syncthreads();
    }
    if (tid == 0) {
        float per = sd[0];
        if (gts == 0)
            per = (max_b >= 0) ? ((float)max_b + 0.5f) * (1.0f / (float)NB) : 0.0f;
        const bool empty = (gts == 0) && (cntgt == 0);
        const float cwv = cw[c], twv = tw[n];
        const bool valid = (cwv != 0.0f) && !empty;
        segval[seg]   = valid ? per * twv * cwv : 0.0f;   // plain stores; no memset
        segvalid[seg] = valid ? 1u : 0u;
    }
}

__device__ __forceinline__ void final_body(const float* __restrict__ segval,
                                           const unsigned* __restrict__ segvalid,
                                           float* __restrict__ out)
{
    const int tid = threadIdx.x;
    if (tid < 64) {
        float    lv = segval[tid];
        unsigned vv = segvalid[tid];
        for (int off = 32; off > 0; off >>= 1) {
            lv += __shfl_down(lv, off);
            vv += __shfl_down(vv, off);
        }
        if (tid == 0) out[0] = lv / (float)NN / (float)vv;
    }
}

// ---------------- fused cooperative kernel (1 dispatch) ----------------
__global__ __launch_bounds__(256, 8) void lovasz_fused_kernel(
    const float* __restrict__ x, const int* __restrict__ tgt,
    unsigned* __restrict__ partial, float* __restrict__ segval,
    unsigned* __restrict__ segvalid, const float* __restrict__ cw,
    const float* __restrict__ tw, float* __restrict__ out)
{
    __shared__ unsigned hl[2 * NB];   // 16 KB (hist LDS, reused by scan)
    __shared__ unsigned red[768];     // 3 KB
    cg::grid_group grid = cg::this_grid();

    hist_body(x, tgt, partial, 64, blockIdx.x, hl);          // all 2048 blocks
    grid.sync();
    if (blockIdx.x < NSEG * (NB / 256))
        merge_body(partial, 64, blockIdx.x);                 // 512 blocks
    grid.sync();
    if (blockIdx.x < NSEG)
        scan_body(partial, cw, tw, segval, segvalid, 64, blockIdx.x, hl, red);
    grid.sync();
    if (blockIdx.x == 0)
        final_body(segval, segvalid, out);
}

// ---------------- standalone kernels (fallback path) ----------------
__global__ __launch_bounds__(256, 8) void hist_k(
    const float* __restrict__ x, const int* __restrict__ tgt,
    unsigned* __restrict__ partial, int Bn)
{
    __shared__ unsigned hl[2 * NB];
    hist_body(x, tgt, partial, Bn, blockIdx.x, hl);
}

__global__ __launch_bounds__(256) void merge_k(unsigned* __restrict__ partial, int Bn)
{
    merge_body(partial, Bn, blockIdx.x);
}

__global__ __launch_bounds__(256) void scan_k(
    const unsigned* __restrict__ partial, const float* __restrict__ cw,
    const float* __restrict__ tw, float* __restrict__ segval,
    unsigned* __restrict__ segvalid, int Bn)
{
    __shared__ unsigned mh[2 * NB];
    __shared__ unsigned red[768];
    scan_body(partial, cw, tw, segval, segvalid, Bn, blockIdx.x, mh, red);
}

__global__ void final_k(const float* __restrict__ segval,
                        const unsigned* __restrict__ segvalid,
                        float* __restrict__ out)
{
    final_body(segval, segvalid, out);
}

extern "C" void kernel_launch(void* const* d_in, const int* in_sizes, int n_in,
                              void* d_out, int out_size, void* d_ws, size_t ws_size,
                              hipStream_t stream)
{
    const float* x   = (const float*)d_in[0];   // [32,2,512,512] f32
    const int*   tgt = (const int*)d_in[1];     // [32,512,512] int
    const float* cw  = (const float*)d_in[2];   // [2]
    const float* tw  = (const float*)d_in[3];   // [32]
    float* out = (float*)d_out;

    // ws layout: [0,256) segval (64 f32), [256,512) segvalid (64 u32),
    // [512, 512 + NN*Bn*2*NB*4) partial. Bn=64 -> 32 MiB (proven fits).
    float*    segval   = (float*)d_ws;
    unsigned* segvalid = (unsigned*)((char*)d_ws + 256);
    unsigned* partial  = (unsigned*)((char*)d_ws + 512);

    const size_t per_bn = (size_t)NN * 2 * NB * sizeof(unsigned);  // 0.5 MiB
    int Bn = 0;
    if      (ws_size >= 512 + 64 * per_bn) Bn = 64;
    else if (ws_size >= 512 + 32 * per_bn) Bn = 32;
    else                                   Bn = 16;   // 8 MiB min

    bool coop = false;
    if (Bn == 64) {
        int occ = 0, ncu = 0;
        if (hipOccupancyMaxActiveBlocksPerMultiprocessor(
                &occ, lovasz_fused_kernel, 256, 0) == hipSuccess) {
            hipDeviceProp_t prop;
            int dev = 0;
            hipGetDevice(&dev);
            if (hipGetDeviceProperties(&prop, dev) == hipSuccess)
                ncu = prop.multiProcessorCount;
            coop = ((long long)occ * ncu >= (long long)NN * 64);
        }
    }

    if (coop) {
        void* args[] = {(void*)&x, (void*)&tgt, (void*)&partial, (void*)&segval,
                        (void*)&segvalid, (void*)&cw, (void*)&tw, (void*)&out};
        hipLaunchCooperativeKernel((void*)lovasz_fused_kernel,
                                   dim3(NN * 64), dim3(256), args, 0, stream);
    } else {
        hist_k <<<NN * Bn, 256, 0, stream>>>(x, tgt, partial, Bn);
        merge_k<<<NSEG * (NB / 256), 256, 0, stream>>>(partial, Bn);
        scan_k <<<NSEG, 256, 0, stream>>>(partial, cw, tw, segval, segvalid, Bn);
        final_k<<<1, 64, 0, stream>>>(segval, segvalid, out);
    }
}